// Round 3
// baseline (123.218 us; speedup 1.0000x reference)
//
#include <hip/hip_runtime.h>
#include <stdint.h>

#define TT 192
#define DIMM 512

typedef float f32x4 __attribute__((ext_vector_type(4)));
typedef short s16x8 __attribute__((ext_vector_type(8)));
typedef _Float16 h16x8 __attribute__((ext_vector_type(8)));

#if __has_builtin(__builtin_amdgcn_exp2f)
#define EXP2(x) __builtin_amdgcn_exp2f(x)
#else
#define EXP2(x) exp2f(x)
#endif

__device__ __forceinline__ float bf2f(uint16_t b) {
    union { uint32_t u; float f; } v; v.u = ((uint32_t)b) << 16; return v.f;
}
__device__ __forceinline__ uint16_t f2bf(float f) {
    union { float f; uint32_t u; } v; v.f = f;
    uint32_t u = v.u;
    uint32_t r = (u + 0x7FFFu + ((u >> 16) & 1u)) >> 16;   // RTN-even
    return (uint16_t)r;
}
__device__ __forceinline__ uint16_t f2h(float f) {
    union { _Float16 h; uint16_t u; } v; v.h = (_Float16)f; return v.u;
}

// ---------------- LayerNorm: x fp32 [384][512] -> xn bf16 ----------------
__global__ __launch_bounds__(256) void k_ln(const float* __restrict__ x,
                                            const float* __restrict__ gamma,
                                            const float* __restrict__ beta,
                                            uint16_t* __restrict__ xn) {
    int row = blockIdx.x;
    int tid = threadIdx.x;
    const float* xr = x + row * DIMM;
    float2 v = *(const float2*)(xr + tid * 2);
    float s = v.x + v.y;
    float s2 = v.x * v.x + v.y * v.y;
    for (int off = 32; off; off >>= 1) {
        s  += __shfl_down(s, off);
        s2 += __shfl_down(s2, off);
    }
    __shared__ float ws1[4], ws2[4];
    int w = tid >> 6, lane = tid & 63;
    if (lane == 0) { ws1[w] = s; ws2[w] = s2; }
    __syncthreads();
    if (tid == 0) {
        float a = 0.f, b = 0.f;
        for (int i = 0; i < 4; i++) { a += ws1[i]; b += ws2[i]; }
        ws1[0] = a; ws2[0] = b;
    }
    __syncthreads();
    float mu = ws1[0] * (1.f / DIMM);
    float var = ws2[0] * (1.f / DIMM) - mu * mu;
    float rs = rsqrtf(var + 1e-5f);
    float o0 = (v.x - mu) * rs * gamma[tid * 2]     + beta[tid * 2];
    float o1 = (v.y - mu) * rs * gamma[tid * 2 + 1] + beta[tid * 2 + 1];
    uint32_t pk = (uint32_t)f2bf(o0) | ((uint32_t)f2bf(o1) << 16);
    *(uint32_t*)(xn + row * DIMM + tid * 2) = pk;
}

// ---------- proj GEMM: xn[384][512]bf16 @ W[2560][512]f32^T + bias ----------
// epilogue scatters into comp[5][2][8][192][64] fp16
__global__ __launch_bounds__(256) void k_gemm_proj(const uint16_t* __restrict__ A,
                                                   const float* __restrict__ B,
                                                   const float* __restrict__ bias,
                                                   uint16_t* __restrict__ comp) {
    __shared__ uint16_t Asm[64][40];
    __shared__ uint16_t Bsm[64][40];
    int n0 = blockIdx.x * 64, m0 = blockIdx.y * 64;
    int tid = threadIdx.x;
    int lr = tid >> 2, seg = tid & 3;
    int w = tid >> 6, lane = tid & 63, g = lane >> 4, c = lane & 15;
    f32x4 acc[4] = {};
    for (int k0 = 0; k0 < 512; k0 += 32) {
        *(s16x8*)(&Asm[lr][seg * 8]) = *(const s16x8*)(A + (m0 + lr) * 512 + k0 + seg * 8);
        float4 b0 = *(const float4*)(B + (n0 + lr) * 512 + k0 + seg * 8);
        float4 b1 = *(const float4*)(B + (n0 + lr) * 512 + k0 + seg * 8 + 4);
        s16x8 bq;
        bq[0] = (short)f2bf(b0.x); bq[1] = (short)f2bf(b0.y);
        bq[2] = (short)f2bf(b0.z); bq[3] = (short)f2bf(b0.w);
        bq[4] = (short)f2bf(b1.x); bq[5] = (short)f2bf(b1.y);
        bq[6] = (short)f2bf(b1.z); bq[7] = (short)f2bf(b1.w);
        *(s16x8*)(&Bsm[lr][seg * 8]) = bq;
        __syncthreads();
        s16x8 af = *(const s16x8*)(&Asm[w * 16 + c][g * 8]);
#pragma unroll
        for (int nt = 0; nt < 4; nt++) {
            s16x8 bf = *(const s16x8*)(&Bsm[nt * 16 + c][g * 8]);
            acc[nt] = __builtin_amdgcn_mfma_f32_16x16x32_bf16(af, bf, acc[nt], 0, 0, 0);
        }
        __syncthreads();
    }
    // epilogue: n -> (cmp, h, dh); m -> (bb, t)
    int cmp = n0 / 512;
    int h   = (n0 % 512) / 64;
    int bb  = m0 / 192;
    int t0  = m0 % 192;
    uint16_t* base = comp + (((size_t)(cmp * 2 + bb) * 8 + h) * TT) * 64;
#pragma unroll
    for (int nt = 0; nt < 4; nt++) {
        int dh = nt * 16 + c;
        float bv = bias[n0 + nt * 16 + c];
#pragma unroll
        for (int r = 0; r < 4; r++) {
            int t = t0 + w * 16 + g * 4 + r;
            base[t * 64 + dh] = f2h(acc[nt][r] + bv);
        }
    }
}

// ---------------- fused trittention (l-split, fp16) ----------------
// grid (12 qtiles, 4 lchunks, 16 b*h), 256 threads (4 waves)
// wave w handles l in [lc*48 + w*12, +12), all 192 r, q-tile of 16.
__global__ __launch_bounds__(256, 2) void k_tritt(const uint16_t* __restrict__ compu,
                                                  float* __restrict__ zaccG4,
                                                  float* __restrict__ Zpart) {
    __shared__ _Float16 ET[64][232];   // E^T [d][r], stride 464B (16B-aligned, 2-way banks)
    __shared__ _Float16 DT2[64][72];   // D^T [d][l_local], stride 144B (16B-aligned, 2-way)
    __shared__ float Prw[16][204];     // Pr block-sum [q][r]
    __shared__ float Plw[64][16];      // Pl block [l_local(48, pad 64)][q]
    __shared__ float zdsum[16];

    int qt = blockIdx.x, lc = blockIdx.y, bh = blockIdx.z;
    int bb = bh >> 3, h = bh & 7;
    int q0 = qt * 16, l0 = lc * 48;
    const size_t hs = (size_t)TT * 64;
    const _Float16* comp = (const _Float16*)compu;
    const _Float16* Ac = comp + ((size_t)(0 * 2 + bb) * 8 + h) * hs;
    const _Float16* Bc = comp + ((size_t)(1 * 2 + bb) * 8 + h) * hs;
    const _Float16* Cc = comp + ((size_t)(2 * 2 + bb) * 8 + h) * hs;
    const _Float16* Dc = comp + ((size_t)(3 * 2 + bb) * 8 + h) * hs;
    const _Float16* Ec = comp + ((size_t)(4 * 2 + bb) * 8 + h) * hs;

    int tid = threadIdx.x, w = tid >> 6, lane = tid & 63, g = lane >> 4, c = lane & 15;

    for (int i = tid; i < 16 * 204; i += 256) ((float*)Prw)[i] = 0.f;
    for (int i = tid; i < 64 * 16; i += 256) ((float*)Plw)[i] = 0.f;
    if (tid < 16) zdsum[tid] = 0.f;
    for (int i = tid; i < TT * 64; i += 256) {
        int r = i >> 6, d = i & 63;
        ET[d][r] = Ec[i];
    }
    for (int i = tid; i < 48 * 64; i += 256) {
        int r = i >> 6, d = i & 63;
        DT2[d][r] = Dc[(l0 + r) * 64 + d];
    }
    // zero DT2 pad cols 48..63 (K=64 MFMA reads them; Plw pad is 0 but 0*Inf=NaN)
    for (int i = tid; i < 64 * 8; i += 256) {
        int row = i >> 3, cu = i & 7;
        *(uint32_t*)&DT2[row][48 + cu * 2] = 0u;
    }

    // B-comp fragments in registers: full r=0..191 (12 tiles x 2 k-halves)
    h16x8 bfr[12][2];
#pragma unroll
    for (int rt = 0; rt < 12; rt++)
#pragma unroll
        for (int ks = 0; ks < 2; ks++)
            bfr[rt][ks] = *(const h16x8*)(Bc + (rt * 16 + c) * 64 + ks * 32 + g * 8);
    // C query frags pre-scaled by log2(e)/64 so scores feed exp2 directly
    const _Float16 ksc = (_Float16)0.02254246f;   // log2(e)/64
    h16x8 cre0 = *(const h16x8*)(Cc + (q0 + c) * 64 + g * 8);
    h16x8 cre1 = *(const h16x8*)(Cc + (q0 + c) * 64 + 32 + g * 8);
    cre0 = cre0 * ksc;
    cre1 = cre1 * ksc;
    __syncthreads();

    float pracc[12][4] = {};
    float zden = 0.f;
    int lbase = l0 + w * 12;
    h16x8 pa0 = *(const h16x8*)(Ac + lbase * 64 + g * 8);
    h16x8 pa1 = *(const h16x8*)(Ac + lbase * 64 + 32 + g * 8);
    for (int i = 0; i < 12; i++) {
        h16x8 a0 = pa0, a1 = pa1;
        if (i < 11) {
            pa0 = *(const h16x8*)(Ac + (lbase + i + 1) * 64 + g * 8);
            pa1 = *(const h16x8*)(Ac + (lbase + i + 1) * 64 + 32 + g * 8);
        }
        h16x8 gf0 = a0 * cre0;   // 4x v_pk_mul_f16
        h16x8 gf1 = a1 * cre1;
        float psum = 0.f;
#pragma unroll
        for (int rt = 0; rt < 12; rt++) {
            f32x4 s = {};
            s = __builtin_amdgcn_mfma_f32_16x16x32_f16(bfr[rt][0], gf0, s, 0, 0, 0);
            s = __builtin_amdgcn_mfma_f32_16x16x32_f16(bfr[rt][1], gf1, s, 0, 0, 0);
            float p0 = EXP2(s[0]), p1 = EXP2(s[1]), p2 = EXP2(s[2]), p3 = EXP2(s[3]);
            pracc[rt][0] += p0; pracc[rt][1] += p1;
            pracc[rt][2] += p2; pracc[rt][3] += p3;
            psum += (p0 + p1) + (p2 + p3);
        }
        // full-row sum over all 192 r (reduce the 4 g-groups)
        psum += __shfl_xor(psum, 16);
        psum += __shfl_xor(psum, 32);
        zden += psum;
        // Pl[l][q] into LDS (waves own disjoint l rows -> no atomics)
        if (lane < 16) Plw[w * 12 + i][lane] = psum;
    }
    // block-level Pr reduction into LDS (f32 atomics)
#pragma unroll
    for (int rt = 0; rt < 12; rt++)
#pragma unroll
        for (int reg = 0; reg < 4; reg++)
            atomicAdd(&Prw[c][rt * 16 + 4 * g + reg], pracc[rt][reg]);
    if (lane < 16) atomicAdd(&zdsum[c], zden);
    __syncthreads();

    // z = Pr @ E + Pl @ D : wave w owns d-tile w
    f32x4 zacc = {};
#pragma unroll
    for (int ks = 0; ks < 6; ks++) {
        const float* pr = &Prw[c][32 * ks + g * 8];
        h16x8 af;
#pragma unroll
        for (int j = 0; j < 8; j++) af[j] = (_Float16)pr[j];
        h16x8 ef = *(const h16x8*)&ET[w * 16 + c][32 * ks + g * 8];
        zacc = __builtin_amdgcn_mfma_f32_16x16x32_f16(af, ef, zacc, 0, 0, 0);
    }
#pragma unroll
    for (int ks2 = 0; ks2 < 2; ks2++) {
        h16x8 af;
#pragma unroll
        for (int j = 0; j < 8; j++) af[j] = (_Float16)Plw[ks2 * 32 + g * 8 + j][c];
        h16x8 df = *(const h16x8*)&DT2[w * 16 + c][ks2 * 32 + g * 8];
        zacc = __builtin_amdgcn_mfma_f32_16x16x32_f16(af, df, zacc, 0, 0, 0);
    }
    // store partial z (rows q0+g*4+reg, cols h*64 + w*16 + c)
#pragma unroll
    for (int reg = 0; reg < 4; reg++) {
        zaccG4[((size_t)lc * 384 + bb * 192 + q0 + g * 4 + reg) * 512 + h * 64 + w * 16 + c] = zacc[reg];
    }
    if (tid < 16) Zpart[lc * 3072 + (bb * 8 + h) * 192 + q0 + tid] = zdsum[tid];
}

// ---------- finalize: sum 4 partials, divide by Z, -> Zbuf bf16 ----------
__global__ __launch_bounds__(256) void k_zfin(const float* __restrict__ zaccG4,
                                              const float* __restrict__ Zpart,
                                              uint16_t* __restrict__ Zbuf) {
    int row = blockIdx.x;
    int bb = row / 192, q = row % 192;
    int j = threadIdx.x * 2;
    int h = j >> 6;
    float Zs = 0.f;
#pragma unroll
    for (int lcc = 0; lcc < 4; lcc++) Zs += Zpart[lcc * 3072 + (bb * 8 + h) * 192 + q];
    float inv = 1.0f / Zs;
    float v0 = 0.f, v1 = 0.f;
#pragma unroll
    for (int lcc = 0; lcc < 4; lcc++) {
        const float* p = zaccG4 + ((size_t)lcc * 384 + row) * 512 + j;
        v0 += p[0]; v1 += p[1];
    }
    uint32_t pk = (uint32_t)f2bf(v0 * inv) | ((uint32_t)f2bf(v1 * inv) << 16);
    *(uint32_t*)(Zbuf + (size_t)row * 512 + j) = pk;
}

// ---------- out GEMM: Zbuf[384][512]bf16 @ W_out[512][512]f32^T + bias -> fp32 ----------
__global__ __launch_bounds__(256) void k_gemm_out(const uint16_t* __restrict__ A,
                                                  const float* __restrict__ B,
                                                  const float* __restrict__ bias,
                                                  float* __restrict__ out) {
    __shared__ uint16_t Asm[64][40];
    __shared__ uint16_t Bsm[64][40];
    int n0 = blockIdx.x * 64, m0 = blockIdx.y * 64;
    int tid = threadIdx.x;
    int lr = tid >> 2, seg = tid & 3;
    int w = tid >> 6, lane = tid & 63, g = lane >> 4, c = lane & 15;
    f32x4 acc[4] = {};
    for (int k0 = 0; k0 < 512; k0 += 32) {
        *(s16x8*)(&Asm[lr][seg * 8]) = *(const s16x8*)(A + (m0 + lr) * 512 + k0 + seg * 8);
        float4 b0 = *(const float4*)(B + (n0 + lr) * 512 + k0 + seg * 8);
        float4 b1 = *(const float4*)(B + (n0 + lr) * 512 + k0 + seg * 8 + 4);
        s16x8 bq;
        bq[0] = (short)f2bf(b0.x); bq[1] = (short)f2bf(b0.y);
        bq[2] = (short)f2bf(b0.z); bq[3] = (short)f2bf(b0.w);
        bq[4] = (short)f2bf(b1.x); bq[5] = (short)f2bf(b1.y);
        bq[6] = (short)f2bf(b1.z); bq[7] = (short)f2bf(b1.w);
        *(s16x8*)(&Bsm[lr][seg * 8]) = bq;
        __syncthreads();
        s16x8 af = *(const s16x8*)(&Asm[w * 16 + c][g * 8]);
#pragma unroll
        for (int nt = 0; nt < 4; nt++) {
            s16x8 bf = *(const s16x8*)(&Bsm[nt * 16 + c][g * 8]);
            acc[nt] = __builtin_amdgcn_mfma_f32_16x16x32_bf16(af, bf, acc[nt], 0, 0, 0);
        }
        __syncthreads();
    }
#pragma unroll
    for (int nt = 0; nt < 4; nt++) {
        int n = n0 + nt * 16 + c;
        float bv = bias[n];
#pragma unroll
        for (int r = 0; r < 4; r++) {
            int m = m0 + w * 16 + g * 4 + r;
            out[(size_t)m * 512 + n] = acc[nt][r] + bv;
        }
    }
}

extern "C" void kernel_launch(void* const* d_in, const int* in_sizes, int n_in,
                              void* d_out, int out_size, void* d_ws, size_t ws_size,
                              hipStream_t stream) {
    const float* x     = (const float*)d_in[0];
    const float* gamma = (const float*)d_in[1];
    const float* beta  = (const float*)d_in[2];
    const float* Wab   = (const float*)d_in[3];
    const float* bab   = (const float*)d_in[4];
    const float* Wout  = (const float*)d_in[5];
    const float* bout  = (const float*)d_in[6];
    float* out = (float*)d_out;

    char* ws = (char*)d_ws;
    // region plan (lifetimes disjoint where overlapped):
    // [0, 393216):            xn bf16 (k_ln..k_gemm_proj) then Zbuf bf16 (k_zfin..k_gemm_out)
    // [393216, 2359296):      comp fp16 [5][2][8][192][64]
    // [2359296, 5505024):     zaccG4 f32 [4][384][512]
    // [5505024, 5554176):     Zpart f32 [4][3072]
    uint16_t* xn     = (uint16_t*)ws;
    uint16_t* Zbuf   = (uint16_t*)ws;
    uint16_t* comp   = (uint16_t*)(ws + 393216);
    float*    zaccG4 = (float*)(ws + 2359296);
    float*    Zpart  = (float*)(ws + 5505024);

    k_ln<<<384, 256, 0, stream>>>(x, gamma, beta, xn);
    k_gemm_proj<<<dim3(40, 6), 256, 0, stream>>>(xn, Wab, bab, comp);
    k_tritt<<<dim3(12, 4, 16), 256, 0, stream>>>(comp, zaccG4, Zpart);
    k_zfin<<<384, 256, 0, stream>>>(zaccG4, Zpart, Zbuf);
    k_gemm_out<<<dim3(8, 6), 256, 0, stream>>>(Zbuf, Wout, bout, out);
}

// Round 4
// 85.559 us; speedup vs baseline: 1.4402x; 1.4402x over previous
//
#include <hip/hip_runtime.h>
#include <stdint.h>

#define TT 192
#define DIMM 512

typedef float f32x4 __attribute__((ext_vector_type(4)));
typedef short s16x8 __attribute__((ext_vector_type(8)));
typedef _Float16 h16x8 __attribute__((ext_vector_type(8)));

#if __has_builtin(__builtin_amdgcn_exp2f)
#define EXP2(x) __builtin_amdgcn_exp2f(x)
#else
#define EXP2(x) exp2f(x)
#endif

__device__ __forceinline__ float bf2f(uint16_t b) {
    union { uint32_t u; float f; } v; v.u = ((uint32_t)b) << 16; return v.f;
}
__device__ __forceinline__ uint16_t f2bf(float f) {
    union { float f; uint32_t u; } v; v.f = f;
    uint32_t u = v.u;
    uint32_t r = (u + 0x7FFFu + ((u >> 16) & 1u)) >> 16;   // RTN-even
    return (uint16_t)r;
}
__device__ __forceinline__ uint16_t f2h(float f) {
    union { _Float16 h; uint16_t u; } v; v.h = (_Float16)f; return v.u;
}

// ---------------- LayerNorm: x fp32 [384][512] -> xn bf16 ----------------
__global__ __launch_bounds__(256) void k_ln(const float* __restrict__ x,
                                            const float* __restrict__ gamma,
                                            const float* __restrict__ beta,
                                            uint16_t* __restrict__ xn) {
    int row = blockIdx.x;
    int tid = threadIdx.x;
    const float* xr = x + row * DIMM;
    float2 v = *(const float2*)(xr + tid * 2);
    float s = v.x + v.y;
    float s2 = v.x * v.x + v.y * v.y;
    for (int off = 32; off; off >>= 1) {
        s  += __shfl_down(s, off);
        s2 += __shfl_down(s2, off);
    }
    __shared__ float ws1[4], ws2[4];
    int w = tid >> 6, lane = tid & 63;
    if (lane == 0) { ws1[w] = s; ws2[w] = s2; }
    __syncthreads();
    if (tid == 0) {
        float a = 0.f, b = 0.f;
        for (int i = 0; i < 4; i++) { a += ws1[i]; b += ws2[i]; }
        ws1[0] = a; ws2[0] = b;
    }
    __syncthreads();
    float mu = ws1[0] * (1.f / DIMM);
    float var = ws2[0] * (1.f / DIMM) - mu * mu;
    float rs = rsqrtf(var + 1e-5f);
    float o0 = (v.x - mu) * rs * gamma[tid * 2]     + beta[tid * 2];
    float o1 = (v.y - mu) * rs * gamma[tid * 2 + 1] + beta[tid * 2 + 1];
    uint32_t pk = (uint32_t)f2bf(o0) | ((uint32_t)f2bf(o1) << 16);
    *(uint32_t*)(xn + row * DIMM + tid * 2) = pk;
}

// ---------- proj GEMM: xn[384][512]bf16 @ W[2560][512]f32^T + bias ----------
// epilogue scatters into comp[5][2][8][192][64] fp16
__global__ __launch_bounds__(256) void k_gemm_proj(const uint16_t* __restrict__ A,
                                                   const float* __restrict__ B,
                                                   const float* __restrict__ bias,
                                                   uint16_t* __restrict__ comp) {
    __shared__ uint16_t Asm[64][40];
    __shared__ uint16_t Bsm[64][40];
    int n0 = blockIdx.x * 64, m0 = blockIdx.y * 64;
    int tid = threadIdx.x;
    int lr = tid >> 2, seg = tid & 3;
    int w = tid >> 6, lane = tid & 63, g = lane >> 4, c = lane & 15;
    f32x4 acc[4] = {};
    for (int k0 = 0; k0 < 512; k0 += 32) {
        *(s16x8*)(&Asm[lr][seg * 8]) = *(const s16x8*)(A + (m0 + lr) * 512 + k0 + seg * 8);
        float4 b0 = *(const float4*)(B + (n0 + lr) * 512 + k0 + seg * 8);
        float4 b1 = *(const float4*)(B + (n0 + lr) * 512 + k0 + seg * 8 + 4);
        s16x8 bq;
        bq[0] = (short)f2bf(b0.x); bq[1] = (short)f2bf(b0.y);
        bq[2] = (short)f2bf(b0.z); bq[3] = (short)f2bf(b0.w);
        bq[4] = (short)f2bf(b1.x); bq[5] = (short)f2bf(b1.y);
        bq[6] = (short)f2bf(b1.z); bq[7] = (short)f2bf(b1.w);
        *(s16x8*)(&Bsm[lr][seg * 8]) = bq;
        __syncthreads();
        s16x8 af = *(const s16x8*)(&Asm[w * 16 + c][g * 8]);
#pragma unroll
        for (int nt = 0; nt < 4; nt++) {
            s16x8 bf = *(const s16x8*)(&Bsm[nt * 16 + c][g * 8]);
            acc[nt] = __builtin_amdgcn_mfma_f32_16x16x32_bf16(af, bf, acc[nt], 0, 0, 0);
        }
        __syncthreads();
    }
    // epilogue: n -> (cmp, h, dh); m -> (bb, t)
    int cmp = n0 / 512;
    int h   = (n0 % 512) / 64;
    int bb  = m0 / 192;
    int t0  = m0 % 192;
    uint16_t* base = comp + (((size_t)(cmp * 2 + bb) * 8 + h) * TT) * 64;
#pragma unroll
    for (int nt = 0; nt < 4; nt++) {
        int dh = nt * 16 + c;
        float bv = bias[n0 + nt * 16 + c];
#pragma unroll
        for (int r = 0; r < 4; r++) {
            int t = t0 + w * 16 + g * 4 + r;
            base[t * 64 + dh] = f2h(acc[nt][r] + bv);
        }
    }
}

// ---------------- fused trittention (l-split blocks, r-split waves, fp16) ----------------
// grid (12 qtiles, 4 lchunks, 16 b*h), 256 threads (4 waves)
// All waves iterate the block's 48 l values; wave w owns r in [w*48, w*48+48).
__global__ __launch_bounds__(256, 2) void k_tritt(const uint16_t* __restrict__ compu,
                                                  float* __restrict__ zaccG4,
                                                  float* __restrict__ Zpart) {
    __shared__ _Float16 ET[64][200];    // E^T [d][r], stride 400B (16B-aligned)
    __shared__ _Float16 DT2[64][72];    // D^T [d][l_local], stride 144B (16B-aligned)
    __shared__ float Prw[16][205];      // Pr block partial [q][r] (odd-ish stride)
    __shared__ float Plw2[4][48][16];   // per-wave Pl partial [w][l_local][q]
    __shared__ float Plm[64][16];       // merged Pl [l_local pad 64][q]
    __shared__ float zdsum[16];

    int qt = blockIdx.x, lc = blockIdx.y, bh = blockIdx.z;
    int bb = bh >> 3, h = bh & 7;
    int q0 = qt * 16, l0 = lc * 48;
    const size_t hs = (size_t)TT * 64;
    const _Float16* comp = (const _Float16*)compu;
    const _Float16* Ac = comp + ((size_t)(0 * 2 + bb) * 8 + h) * hs;
    const _Float16* Bc = comp + ((size_t)(1 * 2 + bb) * 8 + h) * hs;
    const _Float16* Cc = comp + ((size_t)(2 * 2 + bb) * 8 + h) * hs;
    const _Float16* Dc = comp + ((size_t)(3 * 2 + bb) * 8 + h) * hs;
    const _Float16* Ec = comp + ((size_t)(4 * 2 + bb) * 8 + h) * hs;

    int tid = threadIdx.x, w = tid >> 6, lane = tid & 63, g = lane >> 4, c = lane & 15;

    if (tid < 16) zdsum[tid] = 0.f;
    for (int i = tid; i < 64 * 16; i += 256) ((float*)Plm)[i] = 0.f;
    for (int i = tid; i < TT * 64; i += 256) {
        int r = i >> 6, d = i & 63;
        ET[d][r] = Ec[i];
    }
    for (int i = tid; i < 48 * 64; i += 256) {
        int r = i >> 6, d = i & 63;
        DT2[d][r] = Dc[(l0 + r) * 64 + d];
    }
    // zero DT2 pad cols 48..63 (K=64 MFMA reads them)
    for (int i = tid; i < 64 * 8; i += 256) {
        int row = i >> 3, cu = i & 7;
        *(uint32_t*)&DT2[row][48 + cu * 2] = 0u;
    }

    // B-comp fragments: wave w covers r in [w*48, w*48+48) (3 tiles x 2 k-halves)
    h16x8 bfr[3][2];
#pragma unroll
    for (int rt = 0; rt < 3; rt++)
#pragma unroll
        for (int ks = 0; ks < 2; ks++)
            bfr[rt][ks] = *(const h16x8*)(Bc + (w * 48 + rt * 16 + c) * 64 + ks * 32 + g * 8);
    // C query frags pre-scaled by log2(e)/64 so scores feed exp2 directly
    const _Float16 ksc = (_Float16)0.02254246f;   // log2(e)/64
    h16x8 cre0 = *(const h16x8*)(Cc + (q0 + c) * 64 + g * 8);
    h16x8 cre1 = *(const h16x8*)(Cc + (q0 + c) * 64 + 32 + g * 8);
    cre0 = cre0 * ksc;
    cre1 = cre1 * ksc;
    __syncthreads();

    float pracc[3][4] = {};
    float zden = 0.f;
    h16x8 pa0 = *(const h16x8*)(Ac + l0 * 64 + g * 8);
    h16x8 pa1 = *(const h16x8*)(Ac + l0 * 64 + 32 + g * 8);
    for (int i = 0; i < 48; i++) {
        h16x8 a0 = pa0, a1 = pa1;
        if (i < 47) {
            pa0 = *(const h16x8*)(Ac + (l0 + i + 1) * 64 + g * 8);
            pa1 = *(const h16x8*)(Ac + (l0 + i + 1) * 64 + 32 + g * 8);
        }
        h16x8 gf0 = a0 * cre0;   // 4x v_pk_mul_f16
        h16x8 gf1 = a1 * cre1;
        float psum = 0.f;
#pragma unroll
        for (int rt = 0; rt < 3; rt++) {
            f32x4 s = {};
            s = __builtin_amdgcn_mfma_f32_16x16x32_f16(bfr[rt][0], gf0, s, 0, 0, 0);
            s = __builtin_amdgcn_mfma_f32_16x16x32_f16(bfr[rt][1], gf1, s, 0, 0, 0);
            float p0 = EXP2(s[0]), p1 = EXP2(s[1]), p2 = EXP2(s[2]), p3 = EXP2(s[3]);
            pracc[rt][0] += p0; pracc[rt][1] += p1;
            pracc[rt][2] += p2; pracc[rt][3] += p3;
            psum += (p0 + p1) + (p2 + p3);
        }
        // reduce over the wave's 48 r (sum the 4 g-groups; q = c)
        psum += __shfl_xor(psum, 16);
        psum += __shfl_xor(psum, 32);
        zden += psum;
        if (lane < 16) Plw2[w][i][lane] = psum;   // disjoint per wave, no atomics
    }
    // Pr: waves own disjoint r -> plain stores
#pragma unroll
    for (int rt = 0; rt < 3; rt++)
#pragma unroll
        for (int reg = 0; reg < 4; reg++)
            Prw[c][w * 48 + rt * 16 + 4 * g + reg] = pracc[rt][reg];
    if (lane < 16) atomicAdd(&zdsum[c], zden);
    __syncthreads();
    // merge Pl partials: Plm[l][q] = sum_w Plw2[w][l][q]  (rows 48..63 stay 0)
    for (int i = tid; i < 48 * 16; i += 256) {
        int l = i >> 4, q = i & 15;
        Plm[l][q] = Plw2[0][l][q] + Plw2[1][l][q] + Plw2[2][l][q] + Plw2[3][l][q];
    }
    __syncthreads();

    // z = Pr @ E + Pl @ D : wave w owns d-tile w
    f32x4 zacc = {};
#pragma unroll
    for (int ks = 0; ks < 6; ks++) {
        const float* pr = &Prw[c][32 * ks + g * 8];
        h16x8 af;
#pragma unroll
        for (int j = 0; j < 8; j++) af[j] = (_Float16)pr[j];
        h16x8 ef = *(const h16x8*)&ET[w * 16 + c][32 * ks + g * 8];
        zacc = __builtin_amdgcn_mfma_f32_16x16x32_f16(af, ef, zacc, 0, 0, 0);
    }
#pragma unroll
    for (int ks2 = 0; ks2 < 2; ks2++) {
        h16x8 af;
#pragma unroll
        for (int j = 0; j < 8; j++) af[j] = (_Float16)Plm[ks2 * 32 + g * 8 + j][c];
        h16x8 df = *(const h16x8*)&DT2[w * 16 + c][ks2 * 32 + g * 8];
        zacc = __builtin_amdgcn_mfma_f32_16x16x32_f16(af, df, zacc, 0, 0, 0);
    }
    // store partial z (rows q0+g*4+reg, cols h*64 + w*16 + c)
#pragma unroll
    for (int reg = 0; reg < 4; reg++) {
        zaccG4[((size_t)lc * 384 + bb * 192 + q0 + g * 4 + reg) * 512 + h * 64 + w * 16 + c] = zacc[reg];
    }
    if (tid < 16) Zpart[lc * 3072 + (bb * 8 + h) * 192 + q0 + tid] = zdsum[tid];
}

// ---------- finalize: sum 4 partials, divide by Z, -> Zbuf bf16 ----------
__global__ __launch_bounds__(256) void k_zfin(const float* __restrict__ zaccG4,
                                              const float* __restrict__ Zpart,
                                              uint16_t* __restrict__ Zbuf) {
    int row = blockIdx.x;
    int bb = row / 192, q = row % 192;
    int j = threadIdx.x * 2;
    int h = j >> 6;
    float Zs = 0.f;
#pragma unroll
    for (int lcc = 0; lcc < 4; lcc++) Zs += Zpart[lcc * 3072 + (bb * 8 + h) * 192 + q];
    float inv = 1.0f / Zs;
    float v0 = 0.f, v1 = 0.f;
#pragma unroll
    for (int lcc = 0; lcc < 4; lcc++) {
        const float* p = zaccG4 + ((size_t)lcc * 384 + row) * 512 + j;
        v0 += p[0]; v1 += p[1];
    }
    uint32_t pk = (uint32_t)f2bf(v0 * inv) | ((uint32_t)f2bf(v1 * inv) << 16);
    *(uint32_t*)(Zbuf + (size_t)row * 512 + j) = pk;
}

// ---------- out GEMM: Zbuf[384][512]bf16 @ W_out[512][512]f32^T + bias -> fp32 ----------
__global__ __launch_bounds__(256) void k_gemm_out(const uint16_t* __restrict__ A,
                                                  const float* __restrict__ B,
                                                  const float* __restrict__ bias,
                                                  float* __restrict__ out) {
    __shared__ uint16_t Asm[64][40];
    __shared__ uint16_t Bsm[64][40];
    int n0 = blockIdx.x * 64, m0 = blockIdx.y * 64;
    int tid = threadIdx.x;
    int lr = tid >> 2, seg = tid & 3;
    int w = tid >> 6, lane = tid & 63, g = lane >> 4, c = lane & 15;
    f32x4 acc[4] = {};
    for (int k0 = 0; k0 < 512; k0 += 32) {
        *(s16x8*)(&Asm[lr][seg * 8]) = *(const s16x8*)(A + (m0 + lr) * 512 + k0 + seg * 8);
        float4 b0 = *(const float4*)(B + (n0 + lr) * 512 + k0 + seg * 8);
        float4 b1 = *(const float4*)(B + (n0 + lr) * 512 + k0 + seg * 8 + 4);
        s16x8 bq;
        bq[0] = (short)f2bf(b0.x); bq[1] = (short)f2bf(b0.y);
        bq[2] = (short)f2bf(b0.z); bq[3] = (short)f2bf(b0.w);
        bq[4] = (short)f2bf(b1.x); bq[5] = (short)f2bf(b1.y);
        bq[6] = (short)f2bf(b1.z); bq[7] = (short)f2bf(b1.w);
        *(s16x8*)(&Bsm[lr][seg * 8]) = bq;
        __syncthreads();
        s16x8 af = *(const s16x8*)(&Asm[w * 16 + c][g * 8]);
#pragma unroll
        for (int nt = 0; nt < 4; nt++) {
            s16x8 bf = *(const s16x8*)(&Bsm[nt * 16 + c][g * 8]);
            acc[nt] = __builtin_amdgcn_mfma_f32_16x16x32_bf16(af, bf, acc[nt], 0, 0, 0);
        }
        __syncthreads();
    }
#pragma unroll
    for (int nt = 0; nt < 4; nt++) {
        int n = n0 + nt * 16 + c;
        float bv = bias[n];
#pragma unroll
        for (int r = 0; r < 4; r++) {
            int m = m0 + w * 16 + g * 4 + r;
            out[(size_t)m * 512 + n] = acc[nt][r] + bv;
        }
    }
}

extern "C" void kernel_launch(void* const* d_in, const int* in_sizes, int n_in,
                              void* d_out, int out_size, void* d_ws, size_t ws_size,
                              hipStream_t stream) {
    const float* x     = (const float*)d_in[0];
    const float* gamma = (const float*)d_in[1];
    const float* beta  = (const float*)d_in[2];
    const float* Wab   = (const float*)d_in[3];
    const float* bab   = (const float*)d_in[4];
    const float* Wout  = (const float*)d_in[5];
    const float* bout  = (const float*)d_in[6];
    float* out = (float*)d_out;

    char* ws = (char*)d_ws;
    // region plan (lifetimes disjoint where overlapped):
    // [0, 393216):            xn bf16 (k_ln..k_gemm_proj) then Zbuf bf16 (k_zfin..k_gemm_out)
    // [393216, 2359296):      comp fp16 [5][2][8][192][64]
    // [2359296, 5505024):     zaccG4 f32 [4][384][512]
    // [5505024, 5554176):     Zpart f32 [4][3072]
    uint16_t* xn     = (uint16_t*)ws;
    uint16_t* Zbuf   = (uint16_t*)ws;
    uint16_t* comp   = (uint16_t*)(ws + 393216);
    float*    zaccG4 = (float*)(ws + 2359296);
    float*    Zpart  = (float*)(ws + 5505024);

    k_ln<<<384, 256, 0, stream>>>(x, gamma, beta, xn);
    k_gemm_proj<<<dim3(40, 6), 256, 0, stream>>>(xn, Wab, bab, comp);
    k_tritt<<<dim3(12, 4, 16), 256, 0, stream>>>(comp, zaccG4, Zpart);
    k_zfin<<<384, 256, 0, stream>>>(zaccG4, Zpart, Zbuf);
    k_gemm_out<<<dim3(8, 6), 256, 0, stream>>>(Zbuf, Wout, bout, out);
}

// Round 5
// 82.499 us; speedup vs baseline: 1.4936x; 1.0371x over previous
//
#include <hip/hip_runtime.h>
#include <stdint.h>

#define TT 192
#define DIMM 512

typedef float f32x4 __attribute__((ext_vector_type(4)));
typedef short s16x8 __attribute__((ext_vector_type(8)));
typedef _Float16 h16x8 __attribute__((ext_vector_type(8)));

#if __has_builtin(__builtin_amdgcn_exp2f)
#define EXP2(x) __builtin_amdgcn_exp2f(x)
#else
#define EXP2(x) exp2f(x)
#endif

__device__ __forceinline__ uint32_t cvtpk_bf16(float lo, float hi) {
    uint32_t r;
    asm("v_cvt_pk_bf16_f32 %0, %1, %2" : "=v"(r) : "v"(lo), "v"(hi));
    return r;
}
__device__ __forceinline__ uint16_t f2h(float f) {
    union { _Float16 h; uint16_t u; } v; v.h = (_Float16)f; return v.u;
}

// ---------------- LayerNorm: x fp32 [384][512] -> xn bf16 ----------------
__global__ __launch_bounds__(256) void k_ln(const float* __restrict__ x,
                                            const float* __restrict__ gamma,
                                            const float* __restrict__ beta,
                                            uint16_t* __restrict__ xn) {
    int row = blockIdx.x;
    int tid = threadIdx.x;
    const float* xr = x + row * DIMM;
    float2 v = *(const float2*)(xr + tid * 2);
    float s = v.x + v.y;
    float s2 = v.x * v.x + v.y * v.y;
    for (int off = 32; off; off >>= 1) {
        s  += __shfl_down(s, off);
        s2 += __shfl_down(s2, off);
    }
    __shared__ float ws1[4], ws2[4];
    int w = tid >> 6, lane = tid & 63;
    if (lane == 0) { ws1[w] = s; ws2[w] = s2; }
    __syncthreads();
    if (tid == 0) {
        float a = 0.f, b = 0.f;
        for (int i = 0; i < 4; i++) { a += ws1[i]; b += ws2[i]; }
        ws1[0] = a; ws2[0] = b;
    }
    __syncthreads();
    float mu = ws1[0] * (1.f / DIMM);
    float var = ws2[0] * (1.f / DIMM) - mu * mu;
    float rs = rsqrtf(var + 1e-5f);
    float o0 = (v.x - mu) * rs * gamma[tid * 2]     + beta[tid * 2];
    float o1 = (v.y - mu) * rs * gamma[tid * 2 + 1] + beta[tid * 2 + 1];
    *(uint32_t*)(xn + row * DIMM + tid * 2) = cvtpk_bf16(o0, o1);
}

// ---------- proj GEMM: xn[384][512]bf16 @ W[2560][512]f32^T + bias ----------
// epilogue scatters into comp[5][2][8][192][64] fp16
__global__ __launch_bounds__(256) void k_gemm_proj(const uint16_t* __restrict__ A,
                                                   const float* __restrict__ B,
                                                   const float* __restrict__ bias,
                                                   uint16_t* __restrict__ comp) {
    __shared__ uint16_t Asm[64][40];
    __shared__ uint16_t Bsm[64][40];
    int n0 = blockIdx.x * 64, m0 = blockIdx.y * 64;
    int tid = threadIdx.x;
    int lr = tid >> 2, seg = tid & 3;
    int w = tid >> 6, lane = tid & 63, g = (lane >> 4) & 3, c = lane & 15;
    f32x4 acc[4] = {};
    const uint16_t* Aptr = A + (m0 + lr) * 512 + seg * 8;
    const float*    Bptr = B + (n0 + lr) * 512 + seg * 8;
    s16x8  aCur = *(const s16x8*)(Aptr);
    float4 b0c  = *(const float4*)(Bptr);
    float4 b1c  = *(const float4*)(Bptr + 4);
    for (int k0 = 0; k0 < 512; k0 += 32) {
        *(s16x8*)(&Asm[lr][seg * 8]) = aCur;
        uint4 bq;
        bq.x = cvtpk_bf16(b0c.x, b0c.y);
        bq.y = cvtpk_bf16(b0c.z, b0c.w);
        bq.z = cvtpk_bf16(b1c.x, b1c.y);
        bq.w = cvtpk_bf16(b1c.z, b1c.w);
        *(uint4*)(&Bsm[lr][seg * 8]) = bq;
        if (k0 < 480) {   // issue next-step loads; they complete under the MFMA phase
            aCur = *(const s16x8*)(Aptr + k0 + 32);
            b0c  = *(const float4*)(Bptr + k0 + 32);
            b1c  = *(const float4*)(Bptr + k0 + 36);
        }
        __syncthreads();
        s16x8 af = *(const s16x8*)(&Asm[w * 16 + c][g * 8]);
#pragma unroll
        for (int nt = 0; nt < 4; nt++) {
            s16x8 bf = *(const s16x8*)(&Bsm[nt * 16 + c][g * 8]);
            acc[nt] = __builtin_amdgcn_mfma_f32_16x16x32_bf16(af, bf, acc[nt], 0, 0, 0);
        }
        __syncthreads();
    }
    // epilogue: n -> (cmp, h, dh); m -> (bb, t)
    int cmp = n0 / 512;
    int h   = (n0 % 512) / 64;
    int bb  = m0 / 192;
    int t0  = m0 % 192;
    uint16_t* base = comp + (((size_t)(cmp * 2 + bb) * 8 + h) * TT) * 64;
#pragma unroll
    for (int nt = 0; nt < 4; nt++) {
        int dh = nt * 16 + c;
        float bv = bias[n0 + nt * 16 + c];
#pragma unroll
        for (int r = 0; r < 4; r++) {
            int t = t0 + w * 16 + g * 4 + r;
            base[t * 64 + dh] = f2h(acc[nt][r] + bv);
        }
    }
}

// ---------------- fused trittention (l-split blocks, r-split waves, fp16) ----------------
// grid (12 qtiles, 4 lchunks, 16 b*h), 256 threads (4 waves)
// All waves iterate the block's 48 l values; wave w owns r in [w*48, w*48+48).
__global__ __launch_bounds__(256, 4) void k_tritt(const uint16_t* __restrict__ compu,
                                                  float* __restrict__ zaccG4,
                                                  float* __restrict__ Zpart) {
    __shared__ float Plg[64][69];   // Pl partial [l_local(48,pad64)][g*17 + q]; merged at epilogue
    __shared__ float Prw[16][209];  // Pr block [q][r]
    __shared__ float zdsum[16];

    int qt = blockIdx.x, lc = blockIdx.y, bh = blockIdx.z;
    int bb = bh >> 3, h = bh & 7;
    int q0 = qt * 16, l0 = lc * 48;
    const size_t hs = (size_t)TT * 64;
    const _Float16* comp = (const _Float16*)compu;
    const _Float16* Ac = comp + ((size_t)(0 * 2 + bb) * 8 + h) * hs;
    const _Float16* Bc = comp + ((size_t)(1 * 2 + bb) * 8 + h) * hs;
    const _Float16* Cc = comp + ((size_t)(2 * 2 + bb) * 8 + h) * hs;
    const _Float16* Dc = comp + ((size_t)(3 * 2 + bb) * 8 + h) * hs;
    const _Float16* Ec = comp + ((size_t)(4 * 2 + bb) * 8 + h) * hs;

    int tid = threadIdx.x, w = tid >> 6, lane = tid & 63, g = (lane >> 4) & 3, c = lane & 15;

    for (int i = tid; i < 64 * 69; i += 256) ((float*)Plg)[i] = 0.f;
    if (tid < 16) zdsum[tid] = 0.f;

    // B-comp fragments: wave w covers r in [w*48, w*48+48) (3 tiles x 2 k-halves)
    h16x8 bfr[3][2];
#pragma unroll
    for (int rt = 0; rt < 3; rt++)
#pragma unroll
        for (int ks = 0; ks < 2; ks++)
            bfr[rt][ks] = *(const h16x8*)(Bc + (w * 48 + rt * 16 + c) * 64 + ks * 32 + g * 8);
    // C query frags pre-scaled by log2(e)/64 so scores feed exp2 directly
    const _Float16 ksc = (_Float16)0.02254246f;   // log2(e)/64
    h16x8 cre0 = *(const h16x8*)(Cc + (q0 + c) * 64 + g * 8);
    h16x8 cre1 = *(const h16x8*)(Cc + (q0 + c) * 64 + 32 + g * 8);
    cre0 = cre0 * ksc;
    cre1 = cre1 * ksc;
    __syncthreads();

    float pracc[3][4] = {};
    float zden = 0.f;
    const _Float16* Abase = Ac + l0 * 64;
    h16x8 a00 = *(const h16x8*)(Abase + g * 8);
    h16x8 a01 = *(const h16x8*)(Abase + 32 + g * 8);
    h16x8 a10 = *(const h16x8*)(Abase + 64 + g * 8);
    h16x8 a11 = *(const h16x8*)(Abase + 64 + 32 + g * 8);

#define TRIT_BODY(A0, A1, IDX)                                                          \
    {                                                                                   \
        h16x8 gf0 = A0 * cre0;                                                          \
        h16x8 gf1 = A1 * cre1;                                                          \
        float psum = 0.f;                                                               \
        _Pragma("unroll")                                                               \
        for (int rt = 0; rt < 3; rt++) {                                                \
            f32x4 s = {};                                                               \
            s = __builtin_amdgcn_mfma_f32_16x16x32_f16(bfr[rt][0], gf0, s, 0, 0, 0);    \
            s = __builtin_amdgcn_mfma_f32_16x16x32_f16(bfr[rt][1], gf1, s, 0, 0, 0);    \
            float p0 = EXP2(s[0]), p1 = EXP2(s[1]);                                     \
            float p2 = EXP2(s[2]), p3 = EXP2(s[3]);                                     \
            pracc[rt][0] += p0; pracc[rt][1] += p1;                                     \
            pracc[rt][2] += p2; pracc[rt][3] += p3;                                     \
            psum += (p0 + p1) + (p2 + p3);                                              \
        }                                                                               \
        zden += psum;                                                                   \
        atomicAdd(&Plg[IDX][g * 17 + c], psum); /* ds_add_f32, no return -> no wait */  \
    }

    for (int i = 0; i < 48; i += 2) {
        int ip0 = (i + 2 < 48) ? i + 2 : 46;   // clamp (values discarded on last trip)
        h16x8 n00 = *(const h16x8*)(Abase + ip0 * 64 + g * 8);
        h16x8 n01 = *(const h16x8*)(Abase + ip0 * 64 + 32 + g * 8);
        h16x8 n10 = *(const h16x8*)(Abase + (ip0 + 1) * 64 + g * 8);
        h16x8 n11 = *(const h16x8*)(Abase + (ip0 + 1) * 64 + 32 + g * 8);
        TRIT_BODY(a00, a01, i)
        TRIT_BODY(a10, a11, i + 1)
        a00 = n00; a01 = n01; a10 = n10; a11 = n11;
    }
#undef TRIT_BODY

    // Pr: waves own disjoint r -> plain stores
#pragma unroll
    for (int rt = 0; rt < 3; rt++)
#pragma unroll
        for (int reg = 0; reg < 4; reg++)
            Prw[c][w * 48 + rt * 16 + 4 * g + reg] = pracc[rt][reg];
    // zden: combine g-quadrants, then waves
    zden += __shfl_xor(zden, 16);
    zden += __shfl_xor(zden, 32);
    if (lane < 16) atomicAdd(&zdsum[c], zden);
    __syncthreads();

    // z = Pr @ E + Pl @ D : wave w owns d-tile w; E^T/D^T frags gathered from global (L2-hot)
    f32x4 zacc = {};
    int dcol = w * 16 + c;
#pragma unroll
    for (int ks = 0; ks < 6; ks++) {
        h16x8 af, ef;
#pragma unroll
        for (int j = 0; j < 8; j++) {
            int r = 32 * ks + 8 * g + j;
            af[j] = (_Float16)Prw[c][r];
            ef[j] = Ec[r * 64 + dcol];
        }
        zacc = __builtin_amdgcn_mfma_f32_16x16x32_f16(af, ef, zacc, 0, 0, 0);
    }
#pragma unroll
    for (int ks2 = 0; ks2 < 2; ks2++) {
        h16x8 af, df;
#pragma unroll
        for (int j = 0; j < 8; j++) {
            int ll = 32 * ks2 + 8 * g + j;   // 0..63; rows >=48 are zero-padded in Plg
            float v = (Plg[ll][c] + Plg[ll][17 + c]) + (Plg[ll][34 + c] + Plg[ll][51 + c]);
            af[j] = (_Float16)v;
            df[j] = Dc[(l0 + ll) * 64 + dcol];   // in-bounds of comp; multiplied by 0 for ll>=48
        }
        zacc = __builtin_amdgcn_mfma_f32_16x16x32_f16(af, df, zacc, 0, 0, 0);
    }
    // store partial z (rows q0+g*4+reg, cols h*64 + dcol)
#pragma unroll
    for (int reg = 0; reg < 4; reg++) {
        zaccG4[((size_t)lc * 384 + bb * 192 + q0 + g * 4 + reg) * 512 + h * 64 + dcol] = zacc[reg];
    }
    if (tid < 16) Zpart[lc * 3072 + (bb * 8 + h) * 192 + q0 + tid] = zdsum[tid];
}

// ---------- finalize: sum 4 partials, divide by Z, -> Zbuf bf16 ----------
__global__ __launch_bounds__(256) void k_zfin(const float* __restrict__ zaccG4,
                                              const float* __restrict__ Zpart,
                                              uint16_t* __restrict__ Zbuf) {
    int row = blockIdx.x;
    int bb = row / 192, q = row % 192;
    int j = threadIdx.x * 2;
    int h = j >> 6;
    float Zs = 0.f;
#pragma unroll
    for (int lcc = 0; lcc < 4; lcc++) Zs += Zpart[lcc * 3072 + (bb * 8 + h) * 192 + q];
    float inv = 1.0f / Zs;
    float v0 = 0.f, v1 = 0.f;
#pragma unroll
    for (int lcc = 0; lcc < 4; lcc++) {
        const float* p = zaccG4 + ((size_t)lcc * 384 + row) * 512 + j;
        v0 += p[0]; v1 += p[1];
    }
    *(uint32_t*)(Zbuf + (size_t)row * 512 + j) = cvtpk_bf16(v0 * inv, v1 * inv);
}

// ---------- out GEMM: Zbuf[384][512]bf16 @ W_out[512][512]f32^T + bias -> fp32 ----------
__global__ __launch_bounds__(256) void k_gemm_out(const uint16_t* __restrict__ A,
                                                  const float* __restrict__ B,
                                                  const float* __restrict__ bias,
                                                  float* __restrict__ out) {
    __shared__ uint16_t Asm[64][40];
    __shared__ uint16_t Bsm[64][40];
    int n0 = blockIdx.x * 64, m0 = blockIdx.y * 64;
    int tid = threadIdx.x;
    int lr = tid >> 2, seg = tid & 3;
    int w = tid >> 6, lane = tid & 63, g = (lane >> 4) & 3, c = lane & 15;
    f32x4 acc[4] = {};
    const uint16_t* Aptr = A + (m0 + lr) * 512 + seg * 8;
    const float*    Bptr = B + (n0 + lr) * 512 + seg * 8;
    s16x8  aCur = *(const s16x8*)(Aptr);
    float4 b0c  = *(const float4*)(Bptr);
    float4 b1c  = *(const float4*)(Bptr + 4);
    for (int k0 = 0; k0 < 512; k0 += 32) {
        *(s16x8*)(&Asm[lr][seg * 8]) = aCur;
        uint4 bq;
        bq.x = cvtpk_bf16(b0c.x, b0c.y);
        bq.y = cvtpk_bf16(b0c.z, b0c.w);
        bq.z = cvtpk_bf16(b1c.x, b1c.y);
        bq.w = cvtpk_bf16(b1c.z, b1c.w);
        *(uint4*)(&Bsm[lr][seg * 8]) = bq;
        if (k0 < 480) {
            aCur = *(const s16x8*)(Aptr + k0 + 32);
            b0c  = *(const float4*)(Bptr + k0 + 32);
            b1c  = *(const float4*)(Bptr + k0 + 36);
        }
        __syncthreads();
        s16x8 af = *(const s16x8*)(&Asm[w * 16 + c][g * 8]);
#pragma unroll
        for (int nt = 0; nt < 4; nt++) {
            s16x8 bf = *(const s16x8*)(&Bsm[nt * 16 + c][g * 8]);
            acc[nt] = __builtin_amdgcn_mfma_f32_16x16x32_bf16(af, bf, acc[nt], 0, 0, 0);
        }
        __syncthreads();
    }
#pragma unroll
    for (int nt = 0; nt < 4; nt++) {
        int n = n0 + nt * 16 + c;
        float bv = bias[n];
#pragma unroll
        for (int r = 0; r < 4; r++) {
            int m = m0 + w * 16 + g * 4 + r;
            out[(size_t)m * 512 + n] = acc[nt][r] + bv;
        }
    }
}

extern "C" void kernel_launch(void* const* d_in, const int* in_sizes, int n_in,
                              void* d_out, int out_size, void* d_ws, size_t ws_size,
                              hipStream_t stream) {
    const float* x     = (const float*)d_in[0];
    const float* gamma = (const float*)d_in[1];
    const float* beta  = (const float*)d_in[2];
    const float* Wab   = (const float*)d_in[3];
    const float* bab   = (const float*)d_in[4];
    const float* Wout  = (const float*)d_in[5];
    const float* bout  = (const float*)d_in[6];
    float* out = (float*)d_out;

    char* ws = (char*)d_ws;
    // region plan (lifetimes disjoint where overlapped):
    // [0, 393216):            xn bf16 (k_ln..k_gemm_proj) then Zbuf bf16 (k_zfin..k_gemm_out)
    // [393216, 2359296):      comp fp16 [5][2][8][192][64]
    // [2359296, 5505024):     zaccG4 f32 [4][384][512]
    // [5505024, 5554176):     Zpart f32 [4][3072]
    uint16_t* xn     = (uint16_t*)ws;
    uint16_t* Zbuf   = (uint16_t*)ws;
    uint16_t* comp   = (uint16_t*)(ws + 393216);
    float*    zaccG4 = (float*)(ws + 2359296);
    float*    Zpart  = (float*)(ws + 5505024);

    k_ln<<<384, 256, 0, stream>>>(x, gamma, beta, xn);
    k_gemm_proj<<<dim3(40, 6), 256, 0, stream>>>(xn, Wab, bab, comp);
    k_tritt<<<dim3(12, 4, 16), 256, 0, stream>>>(comp, zaccG4, Zpart);
    k_zfin<<<384, 256, 0, stream>>>(zaccG4, Zpart, Zbuf);
    k_gemm_out<<<dim3(8, 6), 256, 0, stream>>>(Zbuf, Wout, bout, out);
}

// Round 6
// 82.003 us; speedup vs baseline: 1.5026x; 1.0061x over previous
//
#include <hip/hip_runtime.h>
#include <stdint.h>

#define TT 192
#define DIMM 512

typedef float f32x4 __attribute__((ext_vector_type(4)));
typedef short s16x8 __attribute__((ext_vector_type(8)));
typedef _Float16 h16x8 __attribute__((ext_vector_type(8)));

#if __has_builtin(__builtin_amdgcn_exp2f)
#define EXP2(x) __builtin_amdgcn_exp2f(x)
#else
#define EXP2(x) exp2f(x)
#endif

__device__ __forceinline__ uint32_t cvtpk_bf16(float lo, float hi) {
    uint32_t r;
    asm("v_cvt_pk_bf16_f32 %0, %1, %2" : "=v"(r) : "v"(lo), "v"(hi));
    return r;
}
__device__ __forceinline__ uint16_t f2h(float f) {
    union { _Float16 h; uint16_t u; } v; v.h = (_Float16)f; return v.u;
}

// ---------------- LayerNorm: x fp32 [384][512] -> xn bf16 ----------------
__global__ __launch_bounds__(256) void k_ln(const float* __restrict__ x,
                                            const float* __restrict__ gamma,
                                            const float* __restrict__ beta,
                                            uint16_t* __restrict__ xn) {
    int row = blockIdx.x;
    int tid = threadIdx.x;
    const float* xr = x + row * DIMM;
    float2 v = *(const float2*)(xr + tid * 2);
    float s = v.x + v.y;
    float s2 = v.x * v.x + v.y * v.y;
    for (int off = 32; off; off >>= 1) {
        s  += __shfl_down(s, off);
        s2 += __shfl_down(s2, off);
    }
    __shared__ float ws1[4], ws2[4];
    int w = tid >> 6, lane = tid & 63;
    if (lane == 0) { ws1[w] = s; ws2[w] = s2; }
    __syncthreads();
    if (tid == 0) {
        float a = 0.f, b = 0.f;
        for (int i = 0; i < 4; i++) { a += ws1[i]; b += ws2[i]; }
        ws1[0] = a; ws2[0] = b;
    }
    __syncthreads();
    float mu = ws1[0] * (1.f / DIMM);
    float var = ws2[0] * (1.f / DIMM) - mu * mu;
    float rs = rsqrtf(var + 1e-5f);
    float o0 = (v.x - mu) * rs * gamma[tid * 2]     + beta[tid * 2];
    float o1 = (v.y - mu) * rs * gamma[tid * 2 + 1] + beta[tid * 2 + 1];
    *(uint32_t*)(xn + row * DIMM + tid * 2) = cvtpk_bf16(o0, o1);
}

// ---------- proj GEMM: xn[384][512]bf16 @ W[2560][512]f32^T + bias ----------
// epilogue scatters into comp[5][2][8][192][64] fp16
__global__ __launch_bounds__(256) void k_gemm_proj(const uint16_t* __restrict__ A,
                                                   const float* __restrict__ B,
                                                   const float* __restrict__ bias,
                                                   uint16_t* __restrict__ comp) {
    __shared__ uint16_t Asm[64][40];
    __shared__ uint16_t Bsm[64][40];
    int n0 = blockIdx.x * 64, m0 = blockIdx.y * 64;
    int tid = threadIdx.x;
    int lr = tid >> 2, seg = tid & 3;
    int w = tid >> 6, lane = tid & 63, g = (lane >> 4) & 3, c = lane & 15;
    f32x4 acc[4] = {};
    const uint16_t* Aptr = A + (m0 + lr) * 512 + seg * 8;
    const float*    Bptr = B + (n0 + lr) * 512 + seg * 8;
    s16x8  aCur = *(const s16x8*)(Aptr);
    float4 b0c  = *(const float4*)(Bptr);
    float4 b1c  = *(const float4*)(Bptr + 4);
    for (int k0 = 0; k0 < 512; k0 += 32) {
        *(s16x8*)(&Asm[lr][seg * 8]) = aCur;
        uint4 bq;
        bq.x = cvtpk_bf16(b0c.x, b0c.y);
        bq.y = cvtpk_bf16(b0c.z, b0c.w);
        bq.z = cvtpk_bf16(b1c.x, b1c.y);
        bq.w = cvtpk_bf16(b1c.z, b1c.w);
        *(uint4*)(&Bsm[lr][seg * 8]) = bq;
        if (k0 < 480) {   // issue next-step loads; they complete under the MFMA phase
            aCur = *(const s16x8*)(Aptr + k0 + 32);
            b0c  = *(const float4*)(Bptr + k0 + 32);
            b1c  = *(const float4*)(Bptr + k0 + 36);
        }
        __syncthreads();
        s16x8 af = *(const s16x8*)(&Asm[w * 16 + c][g * 8]);
#pragma unroll
        for (int nt = 0; nt < 4; nt++) {
            s16x8 bf = *(const s16x8*)(&Bsm[nt * 16 + c][g * 8]);
            acc[nt] = __builtin_amdgcn_mfma_f32_16x16x32_bf16(af, bf, acc[nt], 0, 0, 0);
        }
        __syncthreads();
    }
    // epilogue: n -> (cmp, h, dh); m -> (bb, t)
    int cmp = n0 / 512;
    int h   = (n0 % 512) / 64;
    int bb  = m0 / 192;
    int t0  = m0 % 192;
    uint16_t* base = comp + (((size_t)(cmp * 2 + bb) * 8 + h) * TT) * 64;
#pragma unroll
    for (int nt = 0; nt < 4; nt++) {
        int dh = nt * 16 + c;
        float bv = bias[n0 + nt * 16 + c];
#pragma unroll
        for (int r = 0; r < 4; r++) {
            int t = t0 + w * 16 + g * 4 + r;
            base[t * 64 + dh] = f2h(acc[nt][r] + bv);
        }
    }
}

// ---------------- fused trittention (l-split blocks, r-split waves, fp16) ----------------
// grid (12 qtiles, 4 lchunks, 16 b*h), 256 threads (4 waves)
// All waves iterate the block's 48 l values; wave w owns r in [w*48, w*48+48).
__global__ __launch_bounds__(256, 2) void k_tritt(const uint16_t* __restrict__ compu,
                                                  float* __restrict__ zaccG4,
                                                  float* __restrict__ Zpart) {
    __shared__ float Plg[64][69];   // Pl partial [l_local(48,pad64)][g*17 + q]; merged at epilogue
    __shared__ float Prw[16][209];  // Pr block [q][r]
    __shared__ float zdsum[16];

    int qt = blockIdx.x, lc = blockIdx.y, bh = blockIdx.z;
    int bb = bh >> 3, h = bh & 7;
    int q0 = qt * 16, l0 = lc * 48;
    const size_t hs = (size_t)TT * 64;
    const _Float16* comp = (const _Float16*)compu;
    const _Float16* Ac = comp + ((size_t)(0 * 2 + bb) * 8 + h) * hs;
    const _Float16* Bc = comp + ((size_t)(1 * 2 + bb) * 8 + h) * hs;
    const _Float16* Cc = comp + ((size_t)(2 * 2 + bb) * 8 + h) * hs;
    const _Float16* Dc = comp + ((size_t)(3 * 2 + bb) * 8 + h) * hs;
    const _Float16* Ec = comp + ((size_t)(4 * 2 + bb) * 8 + h) * hs;

    int tid = threadIdx.x, w = tid >> 6, lane = tid & 63, g = (lane >> 4) & 3, c = lane & 15;

    for (int i = tid; i < 64 * 69; i += 256) ((float*)Plg)[i] = 0.f;
    if (tid < 16) zdsum[tid] = 0.f;

    // B-comp fragments: wave w covers r in [w*48, w*48+48) (3 tiles x 2 k-halves)
    h16x8 bfr[3][2];
#pragma unroll
    for (int rt = 0; rt < 3; rt++)
#pragma unroll
        for (int ks = 0; ks < 2; ks++)
            bfr[rt][ks] = *(const h16x8*)(Bc + (w * 48 + rt * 16 + c) * 64 + ks * 32 + g * 8);
    // C query frags pre-scaled by log2(e)/64 so scores feed exp2 directly
    const _Float16 ksc = (_Float16)0.02254246f;   // log2(e)/64
    h16x8 cre0 = *(const h16x8*)(Cc + (q0 + c) * 64 + g * 8);
    h16x8 cre1 = *(const h16x8*)(Cc + (q0 + c) * 64 + 32 + g * 8);
    cre0 = cre0 * ksc;
    cre1 = cre1 * ksc;
    __syncthreads();

    float pracc[3][4] = {};
    float zden = 0.f;
    const _Float16* Abase = Ac + l0 * 64;

#define TRIT_BODY(A0, A1, IDX)                                                          \
    {                                                                                   \
        h16x8 gf0 = (A0) * cre0;                                                        \
        h16x8 gf1 = (A1) * cre1;                                                        \
        float psum = 0.f;                                                               \
        _Pragma("unroll")                                                               \
        for (int rt = 0; rt < 3; rt++) {                                                \
            f32x4 s = {};                                                               \
            s = __builtin_amdgcn_mfma_f32_16x16x32_f16(bfr[rt][0], gf0, s, 0, 0, 0);    \
            s = __builtin_amdgcn_mfma_f32_16x16x32_f16(bfr[rt][1], gf1, s, 0, 0, 0);    \
            float p0 = EXP2(s[0]), p1 = EXP2(s[1]);                                     \
            float p2 = EXP2(s[2]), p3 = EXP2(s[3]);                                     \
            pracc[rt][0] += p0; pracc[rt][1] += p1;                                     \
            pracc[rt][2] += p2; pracc[rt][3] += p3;                                     \
            psum += (p0 + p1) + (p2 + p3);                                              \
        }                                                                               \
        zden += psum;                                                                   \
        atomicAdd(&Plg[IDX][g * 17 + c], psum); /* ds_add_f32, no return -> no wait */  \
    }

    // 4-deep prefetch, 4x unrolled body (12 trips x 4 l)
    h16x8 cur0[2], cur1[2], cur2[2], cur3[2];
#pragma unroll
    for (int k = 0; k < 2; k++) {
        cur0[k] = *(const h16x8*)(Abase + 0 * 64 + k * 32 + g * 8);
        cur1[k] = *(const h16x8*)(Abase + 1 * 64 + k * 32 + g * 8);
        cur2[k] = *(const h16x8*)(Abase + 2 * 64 + k * 32 + g * 8);
        cur3[k] = *(const h16x8*)(Abase + 3 * 64 + k * 32 + g * 8);
    }
    for (int trip = 0; trip < 12; trip++) {
        int i0 = trip * 4;
        int nb = (trip < 11) ? i0 + 4 : i0;   // clamp: last trip reloads (discarded)
        h16x8 nxt0[2], nxt1[2], nxt2[2], nxt3[2];
#pragma unroll
        for (int k = 0; k < 2; k++) {
            nxt0[k] = *(const h16x8*)(Abase + (nb + 0) * 64 + k * 32 + g * 8);
            nxt1[k] = *(const h16x8*)(Abase + (nb + 1) * 64 + k * 32 + g * 8);
            nxt2[k] = *(const h16x8*)(Abase + (nb + 2) * 64 + k * 32 + g * 8);
            nxt3[k] = *(const h16x8*)(Abase + (nb + 3) * 64 + k * 32 + g * 8);
        }
        TRIT_BODY(cur0[0], cur0[1], i0)
        TRIT_BODY(cur1[0], cur1[1], i0 + 1)
        TRIT_BODY(cur2[0], cur2[1], i0 + 2)
        TRIT_BODY(cur3[0], cur3[1], i0 + 3)
#pragma unroll
        for (int k = 0; k < 2; k++) {
            cur0[k] = nxt0[k]; cur1[k] = nxt1[k];
            cur2[k] = nxt2[k]; cur3[k] = nxt3[k];
        }
    }
#undef TRIT_BODY

    // Pr: waves own disjoint r -> plain stores
#pragma unroll
    for (int rt = 0; rt < 3; rt++)
#pragma unroll
        for (int reg = 0; reg < 4; reg++)
            Prw[c][w * 48 + rt * 16 + 4 * g + reg] = pracc[rt][reg];
    // zden: combine g-quadrants, then waves
    zden += __shfl_xor(zden, 16);
    zden += __shfl_xor(zden, 32);
    if (lane < 16) atomicAdd(&zdsum[c], zden);
    __syncthreads();

    // z = Pr @ E + Pl @ D : wave w owns d-tile w; E^T/D^T frags gathered from global (L2-hot)
    f32x4 zacc = {};
    int dcol = w * 16 + c;
#pragma unroll
    for (int ks = 0; ks < 6; ks++) {
        h16x8 af, ef;
#pragma unroll
        for (int j = 0; j < 8; j++) {
            int r = 32 * ks + 8 * g + j;
            af[j] = (_Float16)Prw[c][r];
            ef[j] = Ec[r * 64 + dcol];
        }
        zacc = __builtin_amdgcn_mfma_f32_16x16x32_f16(af, ef, zacc, 0, 0, 0);
    }
#pragma unroll
    for (int ks2 = 0; ks2 < 2; ks2++) {
        h16x8 af, df;
#pragma unroll
        for (int j = 0; j < 8; j++) {
            int ll = 32 * ks2 + 8 * g + j;   // 0..63; rows >=48 are zero-padded in Plg
            float v = (Plg[ll][c] + Plg[ll][17 + c]) + (Plg[ll][34 + c] + Plg[ll][51 + c]);
            af[j] = (_Float16)v;
            df[j] = Dc[(l0 + ll) * 64 + dcol];   // in-bounds of comp; multiplied by 0 for ll>=48
        }
        zacc = __builtin_amdgcn_mfma_f32_16x16x32_f16(af, df, zacc, 0, 0, 0);
    }
    // store partial z (rows q0+g*4+reg, cols h*64 + dcol)
#pragma unroll
    for (int reg = 0; reg < 4; reg++) {
        zaccG4[((size_t)lc * 384 + bb * 192 + q0 + g * 4 + reg) * 512 + h * 64 + dcol] = zacc[reg];
    }
    if (tid < 16) Zpart[lc * 3072 + (bb * 8 + h) * 192 + q0 + tid] = zdsum[tid];
}

// ---------- finalize: sum 4 partials, divide by Z, -> Zbuf bf16 ----------
__global__ __launch_bounds__(256) void k_zfin(const float* __restrict__ zaccG4,
                                              const float* __restrict__ Zpart,
                                              uint16_t* __restrict__ Zbuf) {
    int row = blockIdx.x;
    int bb = row / 192, q = row % 192;
    int j = threadIdx.x * 2;
    int h = j >> 6;
    float Zs = 0.f;
#pragma unroll
    for (int lcc = 0; lcc < 4; lcc++) Zs += Zpart[lcc * 3072 + (bb * 8 + h) * 192 + q];
    float inv = 1.0f / Zs;
    float v0 = 0.f, v1 = 0.f;
#pragma unroll
    for (int lcc = 0; lcc < 4; lcc++) {
        const float* p = zaccG4 + ((size_t)lcc * 384 + row) * 512 + j;
        v0 += p[0]; v1 += p[1];
    }
    *(uint32_t*)(Zbuf + (size_t)row * 512 + j) = cvtpk_bf16(v0 * inv, v1 * inv);
}

// ---------- out GEMM: Zbuf[384][512]bf16 @ W_out[512][512]f32^T + bias -> fp32 ----------
__global__ __launch_bounds__(256) void k_gemm_out(const uint16_t* __restrict__ A,
                                                  const float* __restrict__ B,
                                                  const float* __restrict__ bias,
                                                  float* __restrict__ out) {
    __shared__ uint16_t Asm[64][40];
    __shared__ uint16_t Bsm[64][40];
    int n0 = blockIdx.x * 64, m0 = blockIdx.y * 64;
    int tid = threadIdx.x;
    int lr = tid >> 2, seg = tid & 3;
    int w = tid >> 6, lane = tid & 63, g = (lane >> 4) & 3, c = lane & 15;
    f32x4 acc[4] = {};
    const uint16_t* Aptr = A + (m0 + lr) * 512 + seg * 8;
    const float*    Bptr = B + (n0 + lr) * 512 + seg * 8;
    s16x8  aCur = *(const s16x8*)(Aptr);
    float4 b0c  = *(const float4*)(Bptr);
    float4 b1c  = *(const float4*)(Bptr + 4);
    for (int k0 = 0; k0 < 512; k0 += 32) {
        *(s16x8*)(&Asm[lr][seg * 8]) = aCur;
        uint4 bq;
        bq.x = cvtpk_bf16(b0c.x, b0c.y);
        bq.y = cvtpk_bf16(b0c.z, b0c.w);
        bq.z = cvtpk_bf16(b1c.x, b1c.y);
        bq.w = cvtpk_bf16(b1c.z, b1c.w);
        *(uint4*)(&Bsm[lr][seg * 8]) = bq;
        if (k0 < 480) {
            aCur = *(const s16x8*)(Aptr + k0 + 32);
            b0c  = *(const float4*)(Bptr + k0 + 32);
            b1c  = *(const float4*)(Bptr + k0 + 36);
        }
        __syncthreads();
        s16x8 af = *(const s16x8*)(&Asm[w * 16 + c][g * 8]);
#pragma unroll
        for (int nt = 0; nt < 4; nt++) {
            s16x8 bf = *(const s16x8*)(&Bsm[nt * 16 + c][g * 8]);
            acc[nt] = __builtin_amdgcn_mfma_f32_16x16x32_bf16(af, bf, acc[nt], 0, 0, 0);
        }
        __syncthreads();
    }
#pragma unroll
    for (int nt = 0; nt < 4; nt++) {
        int n = n0 + nt * 16 + c;
        float bv = bias[n];
#pragma unroll
        for (int r = 0; r < 4; r++) {
            int m = m0 + w * 16 + g * 4 + r;
            out[(size_t)m * 512 + n] = acc[nt][r] + bv;
        }
    }
}

extern "C" void kernel_launch(void* const* d_in, const int* in_sizes, int n_in,
                              void* d_out, int out_size, void* d_ws, size_t ws_size,
                              hipStream_t stream) {
    const float* x     = (const float*)d_in[0];
    const float* gamma = (const float*)d_in[1];
    const float* beta  = (const float*)d_in[2];
    const float* Wab   = (const float*)d_in[3];
    const float* bab   = (const float*)d_in[4];
    const float* Wout  = (const float*)d_in[5];
    const float* bout  = (const float*)d_in[6];
    float* out = (float*)d_out;

    char* ws = (char*)d_ws;
    // region plan (lifetimes disjoint where overlapped):
    // [0, 393216):            xn bf16 (k_ln..k_gemm_proj) then Zbuf bf16 (k_zfin..k_gemm_out)
    // [393216, 2359296):      comp fp16 [5][2][8][192][64]
    // [2359296, 5505024):     zaccG4 f32 [4][384][512]
    // [5505024, 5554176):     Zpart f32 [4][3072]
    uint16_t* xn     = (uint16_t*)ws;
    uint16_t* Zbuf   = (uint16_t*)ws;
    uint16_t* comp   = (uint16_t*)(ws + 393216);
    float*    zaccG4 = (float*)(ws + 2359296);
    float*    Zpart  = (float*)(ws + 5505024);

    k_ln<<<384, 256, 0, stream>>>(x, gamma, beta, xn);
    k_gemm_proj<<<dim3(40, 6), 256, 0, stream>>>(xn, Wab, bab, comp);
    k_tritt<<<dim3(12, 4, 16), 256, 0, stream>>>(comp, zaccG4, Zpart);
    k_zfin<<<384, 256, 0, stream>>>(zaccG4, Zpart, Zbuf);
    k_gemm_out<<<dim3(8, 6), 256, 0, stream>>>(Zbuf, Wout, bout, out);
}